// Round 19
// baseline (326.205 us; speedup 1.0000x reference)
//
#include <hip/hip_runtime.h>

typedef __attribute__((ext_vector_type(8))) short bf16x8;
typedef __attribute__((ext_vector_type(16))) float f32x16;

#define XD_F 130
#define XD_T 258
#define XD_C 64
#define XD_ELEMS ((size_t)32 * XD_F * XD_T * XD_C)
#define WS_NEEDED ((XD_ELEMS + (size_t)9 * 128 * 64) * 2)

#define SLOTX (130 * 64)   // shorts per conv LDS slot (16,640 B)

// fallback (R18) LDS geometry
#define CPs  72
#define ROWS 130
#define SLOT (ROWS * CPs)
#define FPB  8

__device__ __forceinline__ unsigned short f2bf(float v) {
    unsigned u = __builtin_bit_cast(unsigned, v);
    return (unsigned short)((u + 0x7fffu + ((u >> 16) & 1u)) >> 16);
}

__device__ __forceinline__ float dampf(float tt) {
    return (1.0f - 0.1f * fabsf(tt - 128.f) * (1.f / 128.f))
         * (1.0f - 0.1f * fabsf(tt - 64.f) * (1.f / 64.f));
}

// ---- W reorder: [o][c][kh][kw] f32 -> [k9][o][c] bf16 ----
__global__ __launch_bounds__(256) void prep_w(const float* __restrict__ W,
                                              unsigned short* __restrict__ Wr) {
    int id = blockIdx.x * 256 + threadIdx.x;
    if (id >= 9 * 128 * 64) return;
    int c = id & 63, o = (id >> 6) & 127, k9 = id >> 13;
    Wr[id] = f2bf(W[(o * 64 + c) * 9 + k9]);
}

// ---- x pre-pass: [n][c][f][t] f32 -> damped bf16 xd[n][fpad=f+1][tpad=t+1][c],
//      with zero pads fpad={0,129}, tpad={0,257} ----
__global__ __launch_bounds__(256) void prep_x(const float* __restrict__ x,
                                              unsigned short* __restrict__ xd) {
    __shared__ unsigned short tile[128 * 72];   // pitch 72 shorts: 144B, 16B-aligned rows

    const int tid  = threadIdx.x;
    const int lane = tid & 63;
    const int wid  = tid >> 6;
    const int q    = lane & 3;
    const int p16  = lane >> 2;
    const int n = blockIdx.x >> 7, f = blockIdx.x & 127;

    const unsigned selv = (q & 1) ? 0x07060302u : 0x05040100u;

    float dmp[4][4];
    #pragma unroll
    for (int s = 0; s < 4; ++s)
        #pragma unroll
        for (int j = 0; j < 4; ++j)
            dmp[s][j] = dampf((float)(64 * s + 4 * p16 + j));

    const size_t gout = ((size_t)(n * XD_F + f + 1)) * XD_T * XD_C;

    #pragma unroll 1
    for (int half = 0; half < 2; ++half) {
        const int tb2 = half * 128;
        float4 rb[8];
        #pragma unroll
        for (int j = 0; j < 8; ++j) {
            int c = wid * 16 + (j & 3) * 4 + q;
            int s = j >> 2;
            const float* src = x + ((size_t)(n * 64 + c) * 128 + f) * 256 + tb2 + s * 64 + 4 * p16;
            rb[j] = *(const float4*)src;
        }
        if (half) __syncthreads();   // previous copyout done before tile overwrite
        #pragma unroll
        for (int j = 0; j < 8; ++j) {
            const int s  = j >> 2;
            const int sg = half * 2 + s;
            const int c0 = wid * 16 + (j & 3) * 4;
            float4 v = rb[j];
            unsigned d0 = (unsigned)f2bf(v.x * dmp[sg][0]) | ((unsigned)f2bf(v.y * dmp[sg][1]) << 16);
            unsigned d1 = (unsigned)f2bf(v.z * dmp[sg][2]) | ((unsigned)f2bf(v.w * dmp[sg][3]) << 16);
            // 4x4 u16 quad transpose: lane ends with c0..c0+3 at row 64s+lane
            unsigned p0 = __shfl_xor((int)d0, 2);
            unsigned p1 = __shfl_xor((int)d1, 2);
            bool hi = (lane >> 1) & 1;
            unsigned own = hi ? d1 : d0;
            unsigned oth = hi ? p1 : p0;
            unsigned sown = __shfl_xor((int)own, 1);
            unsigned soth = __shfl_xor((int)oth, 1);
            bool b0 = q & 1, b1 = q & 2;
            unsigned a0 = b0 ? sown : own, a1 = b0 ? own : sown;
            unsigned g0 = b0 ? soth : oth, g1 = b0 ? oth : soth;
            unsigned e0 = b1 ? g0 : a0, e1 = b1 ? g1 : a1;
            unsigned e2 = b1 ? a0 : g0, e3 = b1 ? a1 : g1;
            unsigned r0 = __builtin_amdgcn_perm(e1, e0, selv);
            unsigned r1 = __builtin_amdgcn_perm(e3, e2, selv);
            unsigned* dst = (unsigned*)&tile[(64 * s + lane) * 72 + c0];
            dst[0] = r0;
            dst[1] = r1;
        }
        __syncthreads();
        // coalesced copyout: 128 rows x 64 c
        #pragma unroll
        for (int it = 0; it < 4; ++it) {
            int g = it * 2048 + tid * 8;
            int row = g >> 6, col = g & 63;
            bf16x8 vv = *(const bf16x8*)&tile[row * 72 + col];
            *(bf16x8*)&xd[gout + (size_t)(1 + tb2 + row) * 64 + col] = vv;
        }
    }
    // t pads (tpad = 0 and 257)
    if (tid < 64) {
        int r = tid >> 5, c2 = tid & 31;
        unsigned* pz = (unsigned*)&xd[gout + (size_t)(r ? 257 : 0) * 64];
        pz[c2] = 0u;
    }
    // f pads (fpad = 0 / 129), written by the f==0 / f==127 blocks
    if (f == 0 || f == 127) {
        size_t base = ((size_t)(n * XD_F + (f == 0 ? 0 : 129))) * XD_T * XD_C;
        const bf16x8 z = {0, 0, 0, 0, 0, 0, 0, 0};
        for (int i = tid; i < XD_T * XD_C / 8; i += 256)
            *(bf16x8*)&xd[base + (size_t)i * 8] = z;
    }
}

// ---- main conv (DMA staging): block=(n, t-half, f-group), 4 waves,
//      out 128o x 128t per f; 3-slot ring staged via global_load_lds.
//      LDS row pitch 128B; XOR-involution swizzle (chunk ^= row&7) on
//      DMA SOURCE + read side (rule #21) -> b128 reads at bank floor. ----
__global__ __launch_bounds__(256) void conv_dma(
    const unsigned short* __restrict__ xd, const unsigned short* __restrict__ Wr,
    const float* __restrict__ b, float* __restrict__ out)
{
    __shared__ unsigned short xs[3 * SLOTX];   // 49,920 B

    const int tid  = threadIdx.x;
    const int lane = tid & 63;
    const int wid  = tid >> 6;
    const int lo32 = lane & 31;
    const int kg   = lane >> 5;

    const int raw = blockIdx.x;
    const int logical = (raw & 7) * 128 + (raw >> 3);   // XCD-chunked, bijective
    const int n  = logical >> 5;
    const int th = (logical >> 4) & 1;
    const int f0 = (logical & 15) * FPB;

    const int tb = th * 128;
    const int oh = wid & 1;
    const int tw = wid >> 1;

    auto stage_dma = [&](int fg, int slot) {
        const unsigned short* gbase = xd + ((size_t)(n * XD_F + fg + 1) * XD_T + tb) * 64;
        #pragma unroll
        for (int w = 0; w < 4; ++w) {
            int ch = w * 256 + tid;           // chunk id: rows 0..127
            int r = ch >> 3, p = ch & 7;
            int ps = p ^ (r & 7);             // source chunk for linear dest p
            const unsigned short* src = gbase + r * 64 + ps * 8;
            __builtin_amdgcn_global_load_lds(
                (const __attribute__((address_space(1))) void*)src,
                (__attribute__((address_space(3))) void*)&xs[slot * SLOTX + w * 2048 + wid * 512],
                16, 0, 0);
        }
        if (tid < 16) {                        // tail rows 128,129
            int r = 128 + (tid >> 3), p = tid & 7;
            int ps = p ^ (r & 7);
            bf16x8 v = *(const bf16x8*)(gbase + r * 64 + ps * 8);
            *(bf16x8*)&xs[slot * SLOTX + r * 64 + p * 8] = v;
        }
    };

    f32x16 acc[2][2];

    auto mfma_kh = [&](int kh, int slot) {
        const unsigned short* sb = &xs[slot * SLOTX];
        #pragma unroll
        for (int kw = 0; kw < 3; ++kw) {
            #pragma unroll
            for (int ks = 0; ks < 4; ++ks) {
                bf16x8 af[2];
                #pragma unroll
                for (int fm = 0; fm < 2; ++fm) {
                    int o = oh * 64 + fm * 32 + lo32;
                    af[fm] = *(const bf16x8*)(Wr + (((kh * 3 + kw) * 128 + o) << 6) + ks * 16 + kg * 8);
                }
                #pragma unroll
                for (int fn = 0; fn < 2; ++fn) {
                    int row = tw * 64 + fn * 32 + lo32 + kw;
                    int p = (ks * 2 + kg) ^ (row & 7);
                    bf16x8 bx = *(const bf16x8*)&sb[row * 64 + p * 8];
                    #pragma unroll
                    for (int fm = 0; fm < 2; ++fm)
                        acc[fm][fn] = __builtin_amdgcn_mfma_f32_32x32x16_bf16(
                            af[fm], bx, acc[fm][fn], 0, 0, 0);
                }
            }
        }
    };

    // prologue
    stage_dma(f0 - 1, 0);
    stage_dma(f0,     1);
    stage_dma(f0 + 1, 2);
    __syncthreads();     // drains vmcnt (DMA) + lgkm

    int sA = 0, sB = 1, sC = 2;

    #pragma unroll 1
    for (int i = 0; i < FPB; ++i) {
        const int f = f0 + i;

        #pragma unroll
        for (int a = 0; a < 2; ++a)
            #pragma unroll
            for (int c2 = 0; c2 < 2; ++c2)
                #pragma unroll
                for (int e = 0; e < 16; ++e) acc[a][c2][e] = 0.f;

        mfma_kh(0, sA);
        mfma_kh(1, sB);
        mfma_kh(2, sC);

        // epilogue: C/D layout col=lane&31 (t), row=(reg&3)+8*(reg>>2)+4*(lane>>5)
        #pragma unroll
        for (int fm = 0; fm < 2; ++fm) {
            #pragma unroll
            for (int fn = 0; fn < 2; ++fn) {
                int t = tb + tw * 64 + fn * 32 + lo32;
                #pragma unroll
                for (int reg = 0; reg < 16; ++reg) {
                    int o = oh * 64 + fm * 32 + (reg & 3) + 8 * (reg >> 2) + 4 * kg;
                    out[(((size_t)n * 128 + o) * 128 + f) * 256 + t] = acc[fm][fn][reg] + b[o];
                }
            }
        }

        __syncthreads();                       // all waves done reading slot sA
        if (i < FPB - 1) stage_dma(f + 2, sA); // DMA row f+2 into freed slot
        __syncthreads();                       // drain DMA; slot ready
        int tmp = sA; sA = sB; sB = sC; sC = tmp;
    }
}

// ================= fallback (R18 kernel, used when ws too small) =================
__global__ __launch_bounds__(256) void damp_conv_mfma(
    const float* __restrict__ x, const unsigned short* __restrict__ Wr,
    const float* __restrict__ b, float* __restrict__ out)
{
    __shared__ unsigned short xs[3 * SLOT];

    const int tid  = threadIdx.x;
    const int lane = tid & 63;
    const int wid  = tid >> 6;
    const int q    = lane & 3;
    const int p16  = lane >> 2;
    const int lo32 = lane & 31;
    const int kg   = lane >> 5;

    const int raw = blockIdx.x;
    const int logical = (raw & 7) * 128 + (raw >> 3);
    const int n  = logical >> 5;
    const int th = (logical >> 4) & 1;
    const int f0 = (logical & 15) * FPB;

    const int tb = th * 128;
    const int oh = wid & 1;
    const int tw = wid >> 1;

    const unsigned selv = (q & 1) ? 0x07060302u : 0x05040100u;

    float dmp[2][4];
    #pragma unroll
    for (int s = 0; s < 2; ++s)
        #pragma unroll
        for (int j = 0; j < 4; ++j)
            dmp[s][j] = dampf((float)(tb + 64 * s + 4 * p16 + j));

    const int hside = (tid >> 6) & 1;
    const int hc    = tid & 63;
    const int t_h   = tb + (hside ? 128 : -1);
    const bool tok  = (unsigned)t_h < 256u;
    const float dmp_h = dampf((float)(tok ? t_h : 0));

    float4 rb[8];
    float  hv;

    auto issue_row = [&](int fg) {
        const bool fok = (unsigned)fg < 128u;
        #pragma unroll
        for (int j = 0; j < 8; ++j) {
            int c = wid * 16 + (j & 3) * 4 + q;
            const float* src = x + ((size_t)(n * 64 + c) * 128 + (fok ? fg : 0)) * 256
                             + tb + (j >> 2) * 64 + 4 * p16;
            rb[j] = fok ? *(const float4*)src : (float4){0.f, 0.f, 0.f, 0.f};
        }
        hv = 0.f;
        if (tid < 128 && fok && tok)
            hv = x[((size_t)(n * 64 + hc) * 128 + fg) * 256 + t_h];
    };

    auto write_row = [&](int slot) {
        unsigned short* dstb = &xs[slot * SLOT];
        #pragma unroll
        for (int j = 0; j < 8; ++j) {
            const int s  = j >> 2;
            const int c0 = wid * 16 + (j & 3) * 4;
            float4 v = rb[j];
            unsigned d0 = (unsigned)f2bf(v.x * dmp[s][0]) | ((unsigned)f2bf(v.y * dmp[s][1]) << 16);
            unsigned d1 = (unsigned)f2bf(v.z * dmp[s][2]) | ((unsigned)f2bf(v.w * dmp[s][3]) << 16);
            unsigned p0 = __shfl_xor((int)d0, 2);
            unsigned p1 = __shfl_xor((int)d1, 2);
            bool hi = (lane >> 1) & 1;
            unsigned own = hi ? d1 : d0;
            unsigned oth = hi ? p1 : p0;
            unsigned sown = __shfl_xor((int)own, 1);
            unsigned soth = __shfl_xor((int)oth, 1);
            bool b0 = q & 1, b1 = q & 2;
            unsigned a0 = b0 ? sown : own, a1 = b0 ? own : sown;
            unsigned g0 = b0 ? soth : oth, g1 = b0 ? oth : soth;
            unsigned e0 = b1 ? g0 : a0, e1 = b1 ? g1 : a1;
            unsigned e2 = b1 ? a0 : g0, e3 = b1 ? a1 : g1;
            unsigned r0 = __builtin_amdgcn_perm(e1, e0, selv);
            unsigned r1 = __builtin_amdgcn_perm(e3, e2, selv);
            unsigned* dst = (unsigned*)&dstb[(1 + 64 * s + lane) * CPs + c0];
            dst[0] = r0;
            dst[1] = r1;
        }
        if (tid < 128)
            dstb[(hside ? (ROWS - 1) : 0) * CPs + hc] = f2bf(hv * dmp_h);
    };

    f32x16 acc[2][2];

    auto mfma_kh = [&](int kh, int slot) {
        const unsigned short* sb = &xs[slot * SLOT];
        #pragma unroll
        for (int kw = 0; kw < 3; ++kw) {
            #pragma unroll
            for (int ks = 0; ks < 4; ++ks) {
                const int cb = ks * 16 + kg * 8;
                bf16x8 af[2];
                #pragma unroll
                for (int fm = 0; fm < 2; ++fm) {
                    int o = oh * 64 + fm * 32 + lo32;
                    af[fm] = *(const bf16x8*)(Wr + (((kh * 3 + kw) * 128 + o) << 6) + cb);
                }
                #pragma unroll
                for (int fn = 0; fn < 2; ++fn) {
                    int row = tw * 64 + fn * 32 + lo32 + kw;
                    bf16x8 bx = *(const bf16x8*)&sb[row * CPs + cb];
                    #pragma unroll
                    for (int fm = 0; fm < 2; ++fm)
                        acc[fm][fn] = __builtin_amdgcn_mfma_f32_32x32x16_bf16(
                            af[fm], bx, acc[fm][fn], 0, 0, 0);
                }
            }
        }
    };

    issue_row(f0 - 1); write_row(0);
    issue_row(f0);     write_row(1);
    issue_row(f0 + 1); write_row(2);
    __syncthreads();

    int sA = 0, sB = 1, sC = 2;

    #pragma unroll 1
    for (int i = 0; i < FPB; ++i) {
        const int f = f0 + i;
        if (i < FPB - 1) issue_row(f + 2);

        #pragma unroll
        for (int a = 0; a < 2; ++a)
            #pragma unroll
            for (int c2 = 0; c2 < 2; ++c2)
                #pragma unroll
                for (int e = 0; e < 16; ++e) acc[a][c2][e] = 0.f;

        mfma_kh(0, sA);
        mfma_kh(1, sB);
        mfma_kh(2, sC);

        #pragma unroll
        for (int fm = 0; fm < 2; ++fm) {
            #pragma unroll
            for (int fn = 0; fn < 2; ++fn) {
                int t = tb + tw * 64 + fn * 32 + lo32;
                #pragma unroll
                for (int reg = 0; reg < 16; ++reg) {
                    int o = oh * 64 + fm * 32 + (reg & 3) + 8 * (reg >> 2) + 4 * kg;
                    out[(((size_t)n * 128 + o) * 128 + f) * 256 + t] = acc[fm][fn][reg] + b[o];
                }
            }
        }

        __syncthreads();
        if (i < FPB - 1) write_row(sA);
        __syncthreads();
        int tmp = sA; sA = sB; sB = sC; sC = tmp;
    }
}

extern "C" void kernel_launch(void* const* d_in, const int* in_sizes, int n_in,
                              void* d_out, int out_size, void* d_ws, size_t ws_size,
                              hipStream_t stream) {
    const float* x = (const float*)d_in[0];
    const float* W = (const float*)d_in[1];
    const float* b = (const float*)d_in[2];
    float* out = (float*)d_out;

    if (ws_size >= WS_NEEDED) {
        unsigned short* xd = (unsigned short*)d_ws;
        unsigned short* Wr = xd + XD_ELEMS;
        hipLaunchKernelGGL(prep_w, dim3(288), dim3(256), 0, stream, W, Wr);
        hipLaunchKernelGGL(prep_x, dim3(4096), dim3(256), 0, stream, x, xd);
        hipLaunchKernelGGL(conv_dma, dim3(1024), dim3(256), 0, stream, xd, Wr, b, out);
    } else {
        unsigned short* Wr = (unsigned short*)d_ws;
        hipLaunchKernelGGL(prep_w, dim3(288), dim3(256), 0, stream, W, Wr);
        hipLaunchKernelGGL(damp_conv_mfma, dim3(1024), dim3(256), 0, stream, x, Wr, b, out);
    }
}

// Round 20
// 321.651 us; speedup vs baseline: 1.0142x; 1.0142x over previous
//
#include <hip/hip_runtime.h>

typedef __attribute__((ext_vector_type(8))) short bf16x8;
typedef __attribute__((ext_vector_type(16))) float f32x16;

#define XD_F 130
#define XD_T 258
#define XD_C 64
#define XD_ELEMS ((size_t)32 * XD_F * XD_T * XD_C)
#define WS_NEEDED ((XD_ELEMS + (size_t)9 * 128 * 64) * 2)

#define SLOTX (130 * 64)   // shorts per conv LDS slot (16,640 B)
#define FPBX 16            // f rows per block (DMA path)

// fallback (R18) geometry
#define CPs  72
#define ROWS 130
#define SLOT (ROWS * CPs)
#define FPB  8

__device__ __forceinline__ unsigned short f2bf(float v) {
    unsigned u = __builtin_bit_cast(unsigned, v);
    return (unsigned short)((u + 0x7fffu + ((u >> 16) & 1u)) >> 16);
}

__device__ __forceinline__ float dampf(float tt) {
    return (1.0f - 0.1f * fabsf(tt - 128.f) * (1.f / 128.f))
         * (1.0f - 0.1f * fabsf(tt - 64.f) * (1.f / 64.f));
}

// ---- W reorder: [o][c][kh][kw] f32 -> [k9][o][c] bf16 ----
__global__ __launch_bounds__(256) void prep_w(const float* __restrict__ W,
                                              unsigned short* __restrict__ Wr) {
    int id = blockIdx.x * 256 + threadIdx.x;
    if (id >= 9 * 128 * 64) return;
    int c = id & 63, o = (id >> 6) & 127, k9 = id >> 13;
    Wr[id] = f2bf(W[(o * 64 + c) * 9 + k9]);
}

// ---- x pre-pass: [n][c][f][t] f32 -> damped bf16 xd[n][f+1][t+1][c], zero-padded ----
__global__ __launch_bounds__(256) void prep_x(const float* __restrict__ x,
                                              unsigned short* __restrict__ xd) {
    __shared__ unsigned short tile[128 * 72];

    const int tid  = threadIdx.x;
    const int lane = tid & 63;
    const int wid  = tid >> 6;
    const int q    = lane & 3;
    const int p16  = lane >> 2;
    const int n = blockIdx.x >> 7, f = blockIdx.x & 127;

    const unsigned selv = (q & 1) ? 0x07060302u : 0x05040100u;

    float dmp[4][4];
    #pragma unroll
    for (int s = 0; s < 4; ++s)
        #pragma unroll
        for (int j = 0; j < 4; ++j)
            dmp[s][j] = dampf((float)(64 * s + 4 * p16 + j));

    const size_t gout = ((size_t)(n * XD_F + f + 1)) * XD_T * XD_C;

    #pragma unroll 1
    for (int half = 0; half < 2; ++half) {
        const int tb2 = half * 128;
        float4 rb[8];
        #pragma unroll
        for (int j = 0; j < 8; ++j) {
            int c = wid * 16 + (j & 3) * 4 + q;
            int s = j >> 2;
            const float* src = x + ((size_t)(n * 64 + c) * 128 + f) * 256 + tb2 + s * 64 + 4 * p16;
            rb[j] = *(const float4*)src;
        }
        if (half) __syncthreads();
        #pragma unroll
        for (int j = 0; j < 8; ++j) {
            const int s  = j >> 2;
            const int sg = half * 2 + s;
            const int c0 = wid * 16 + (j & 3) * 4;
            float4 v = rb[j];
            unsigned d0 = (unsigned)f2bf(v.x * dmp[sg][0]) | ((unsigned)f2bf(v.y * dmp[sg][1]) << 16);
            unsigned d1 = (unsigned)f2bf(v.z * dmp[sg][2]) | ((unsigned)f2bf(v.w * dmp[sg][3]) << 16);
            unsigned p0 = __shfl_xor((int)d0, 2);
            unsigned p1 = __shfl_xor((int)d1, 2);
            bool hi = (lane >> 1) & 1;
            unsigned own = hi ? d1 : d0;
            unsigned oth = hi ? p1 : p0;
            unsigned sown = __shfl_xor((int)own, 1);
            unsigned soth = __shfl_xor((int)oth, 1);
            bool b0 = q & 1, b1 = q & 2;
            unsigned a0 = b0 ? sown : own, a1 = b0 ? own : sown;
            unsigned g0 = b0 ? soth : oth, g1 = b0 ? oth : soth;
            unsigned e0 = b1 ? g0 : a0, e1 = b1 ? g1 : a1;
            unsigned e2 = b1 ? a0 : g0, e3 = b1 ? a1 : g1;
            unsigned r0 = __builtin_amdgcn_perm(e1, e0, selv);
            unsigned r1 = __builtin_amdgcn_perm(e3, e2, selv);
            unsigned* dst = (unsigned*)&tile[(64 * s + lane) * 72 + c0];
            dst[0] = r0;
            dst[1] = r1;
        }
        __syncthreads();
        #pragma unroll
        for (int it = 0; it < 4; ++it) {
            int g = it * 2048 + tid * 8;
            int row = g >> 6, col = g & 63;
            bf16x8 vv = *(const bf16x8*)&tile[row * 72 + col];
            *(bf16x8*)&xd[gout + (size_t)(1 + tb2 + row) * 64 + col] = vv;
        }
    }
    if (tid < 64) {
        int r = tid >> 5, c2 = tid & 31;
        unsigned* pz = (unsigned*)&xd[gout + (size_t)(r ? 257 : 0) * 64];
        pz[c2] = 0u;
    }
    if (f == 0 || f == 127) {
        size_t base = ((size_t)(n * XD_F + (f == 0 ? 0 : 129))) * XD_T * XD_C;
        const bf16x8 z = {0, 0, 0, 0, 0, 0, 0, 0};
        for (int i = tid; i < XD_T * XD_C / 8; i += 256)
            *(bf16x8*)&xd[base + (size_t)i * 8] = z;
    }
}

// ---- main conv (async DMA): 4-slot ring (slot=f&3), DMA issued BEFORE the
//      MFMA block, ONE barrier per iter (drain finds DMA complete).
//      Swizzle: rule-#21 involution, verified R19. ----
__global__ __launch_bounds__(256) void conv_dma(
    const unsigned short* __restrict__ xd, const unsigned short* __restrict__ Wr,
    const float* __restrict__ b, float* __restrict__ out)
{
    __shared__ unsigned short xs[4 * SLOTX];   // 66,560 B -> 2 blocks/CU (LDS-wise)

    const int tid  = threadIdx.x;
    const int lane = tid & 63;
    const int wid  = tid >> 6;
    const int lo32 = lane & 31;
    const int kg   = lane >> 5;

    const int raw = blockIdx.x;                 // grid 512
    const int logical = (raw & 7) * 64 + (raw >> 3);   // XCD-chunked, bijective
    const int n  = logical >> 4;
    const int th = (logical >> 3) & 1;
    const int f0 = (logical & 7) * FPBX;

    const int tb = th * 128;
    const int oh = wid & 1;
    const int tw = wid >> 1;

    auto stage_dma = [&](int fg) {
        const int slot = fg & 3;
        const unsigned short* gbase = xd + ((size_t)(n * XD_F + fg + 1) * XD_T + tb) * 64;
        #pragma unroll
        for (int w = 0; w < 4; ++w) {
            int ch = w * 256 + tid;           // chunk id: rows 0..127
            int r = ch >> 3, p = ch & 7;
            int ps = p ^ (r & 7);             // involution: source chunk for linear dest
            const unsigned short* src = gbase + r * 64 + ps * 8;
            __builtin_amdgcn_global_load_lds(
                (const __attribute__((address_space(1))) void*)src,
                (__attribute__((address_space(3))) void*)&xs[slot * SLOTX + w * 2048 + wid * 512],
                16, 0, 0);
        }
        if (tid < 16) {                        // tail rows 128,129
            int r = 128 + (tid >> 3), p = tid & 7;
            int ps = p ^ (r & 7);
            bf16x8 v = *(const bf16x8*)(gbase + r * 64 + ps * 8);
            *(bf16x8*)&xs[slot * SLOTX + r * 64 + p * 8] = v;
        }
    };

    f32x16 acc[2][2];

    auto mfma_kh = [&](int kh, int slot) {
        const unsigned short* sb = &xs[slot * SLOTX];
        #pragma unroll
        for (int kw = 0; kw < 3; ++kw) {
            #pragma unroll
            for (int ks = 0; ks < 4; ++ks) {
                bf16x8 af[2];
                #pragma unroll
                for (int fm = 0; fm < 2; ++fm) {
                    int o = oh * 64 + fm * 32 + lo32;
                    af[fm] = *(const bf16x8*)(Wr + (((kh * 3 + kw) * 128 + o) << 6) + ks * 16 + kg * 8);
                }
                #pragma unroll
                for (int fn = 0; fn < 2; ++fn) {
                    int row = tw * 64 + fn * 32 + lo32 + kw;
                    int p = (ks * 2 + kg) ^ (row & 7);
                    bf16x8 bx = *(const bf16x8*)&sb[row * 64 + p * 8];
                    #pragma unroll
                    for (int fm = 0; fm < 2; ++fm)
                        acc[fm][fn] = __builtin_amdgcn_mfma_f32_32x32x16_bf16(
                            af[fm], bx, acc[fm][fn], 0, 0, 0);
                }
            }
        }
    };

    // prologue: rows f0-1, f0, f0+1 into slots (fr&3)
    stage_dma(f0 - 1);
    stage_dma(f0);
    stage_dma(f0 + 1);
    __syncthreads();     // drains prologue DMA

    #pragma unroll 1
    for (int i = 0; i < FPBX; ++i) {
        const int f = f0 + i;

        // issue next row's DMA FIRST: overlaps with this iter's 432 MFMAs,
        // drained by the end-of-iter barrier (slot (f+2)&3 disjoint from reads)
        if (i < FPBX - 1) stage_dma(f + 2);

        #pragma unroll
        for (int a = 0; a < 2; ++a)
            #pragma unroll
            for (int c2 = 0; c2 < 2; ++c2)
                #pragma unroll
                for (int e = 0; e < 16; ++e) acc[a][c2][e] = 0.f;

        mfma_kh(0, (f - 1) & 3);
        mfma_kh(1, f & 3);
        mfma_kh(2, (f + 1) & 3);

        // epilogue: C/D col=lane&31 (t), row=(reg&3)+8*(reg>>2)+4*(lane>>5)
        #pragma unroll
        for (int fm = 0; fm < 2; ++fm) {
            #pragma unroll
            for (int fn = 0; fn < 2; ++fn) {
                int t = tb + tw * 64 + fn * 32 + lo32;
                #pragma unroll
                for (int reg = 0; reg < 16; ++reg) {
                    int o = oh * 64 + fm * 32 + (reg & 3) + 8 * (reg >> 2) + 4 * kg;
                    out[(((size_t)n * 128 + o) * 128 + f) * 256 + t] = acc[fm][fn][reg] + b[o];
                }
            }
        }

        __syncthreads();   // single barrier: orders reads-done + DMA-complete
    }
}

// ================= fallback (R18 kernel, used when ws too small) =================
__global__ __launch_bounds__(256) void damp_conv_mfma(
    const float* __restrict__ x, const unsigned short* __restrict__ Wr,
    const float* __restrict__ b, float* __restrict__ out)
{
    __shared__ unsigned short xs[3 * SLOT];

    const int tid  = threadIdx.x;
    const int lane = tid & 63;
    const int wid  = tid >> 6;
    const int q    = lane & 3;
    const int p16  = lane >> 2;
    const int lo32 = lane & 31;
    const int kg   = lane >> 5;

    const int raw = blockIdx.x;
    const int logical = (raw & 7) * 128 + (raw >> 3);
    const int n  = logical >> 5;
    const int th = (logical >> 4) & 1;
    const int f0 = (logical & 15) * FPB;

    const int tb = th * 128;
    const int oh = wid & 1;
    const int tw = wid >> 1;

    const unsigned selv = (q & 1) ? 0x07060302u : 0x05040100u;

    float dmp[2][4];
    #pragma unroll
    for (int s = 0; s < 2; ++s)
        #pragma unroll
        for (int j = 0; j < 4; ++j)
            dmp[s][j] = dampf((float)(tb + 64 * s + 4 * p16 + j));

    const int hside = (tid >> 6) & 1;
    const int hc    = tid & 63;
    const int t_h   = tb + (hside ? 128 : -1);
    const bool tok  = (unsigned)t_h < 256u;
    const float dmp_h = dampf((float)(tok ? t_h : 0));

    float4 rb[8];
    float  hv;

    auto issue_row = [&](int fg) {
        const bool fok = (unsigned)fg < 128u;
        #pragma unroll
        for (int j = 0; j < 8; ++j) {
            int c = wid * 16 + (j & 3) * 4 + q;
            const float* src = x + ((size_t)(n * 64 + c) * 128 + (fok ? fg : 0)) * 256
                             + tb + (j >> 2) * 64 + 4 * p16;
            rb[j] = fok ? *(const float4*)src : (float4){0.f, 0.f, 0.f, 0.f};
        }
        hv = 0.f;
        if (tid < 128 && fok && tok)
            hv = x[((size_t)(n * 64 + hc) * 128 + fg) * 256 + t_h];
    };

    auto write_row = [&](int slot) {
        unsigned short* dstb = &xs[slot * SLOT];
        #pragma unroll
        for (int j = 0; j < 8; ++j) {
            const int s  = j >> 2;
            const int c0 = wid * 16 + (j & 3) * 4;
            float4 v = rb[j];
            unsigned d0 = (unsigned)f2bf(v.x * dmp[s][0]) | ((unsigned)f2bf(v.y * dmp[s][1]) << 16);
            unsigned d1 = (unsigned)f2bf(v.z * dmp[s][2]) | ((unsigned)f2bf(v.w * dmp[s][3]) << 16);
            unsigned p0 = __shfl_xor((int)d0, 2);
            unsigned p1 = __shfl_xor((int)d1, 2);
            bool hi = (lane >> 1) & 1;
            unsigned own = hi ? d1 : d0;
            unsigned oth = hi ? p1 : p0;
            unsigned sown = __shfl_xor((int)own, 1);
            unsigned soth = __shfl_xor((int)oth, 1);
            bool b0 = q & 1, b1 = q & 2;
            unsigned a0 = b0 ? sown : own, a1 = b0 ? own : sown;
            unsigned g0 = b0 ? soth : oth, g1 = b0 ? oth : soth;
            unsigned e0 = b1 ? g0 : a0, e1 = b1 ? g1 : a1;
            unsigned e2 = b1 ? a0 : g0, e3 = b1 ? a1 : g1;
            unsigned r0 = __builtin_amdgcn_perm(e1, e0, selv);
            unsigned r1 = __builtin_amdgcn_perm(e3, e2, selv);
            unsigned* dst = (unsigned*)&dstb[(1 + 64 * s + lane) * CPs + c0];
            dst[0] = r0;
            dst[1] = r1;
        }
        if (tid < 128)
            dstb[(hside ? (ROWS - 1) : 0) * CPs + hc] = f2bf(hv * dmp_h);
    };

    f32x16 acc[2][2];

    auto mfma_kh = [&](int kh, int slot) {
        const unsigned short* sb = &xs[slot * SLOT];
        #pragma unroll
        for (int kw = 0; kw < 3; ++kw) {
            #pragma unroll
            for (int ks = 0; ks < 4; ++ks) {
                const int cb = ks * 16 + kg * 8;
                bf16x8 af[2];
                #pragma unroll
                for (int fm = 0; fm < 2; ++fm) {
                    int o = oh * 64 + fm * 32 + lo32;
                    af[fm] = *(const bf16x8*)(Wr + (((kh * 3 + kw) * 128 + o) << 6) + cb);
                }
                #pragma unroll
                for (int fn = 0; fn < 2; ++fn) {
                    int row = tw * 64 + fn * 32 + lo32 + kw;
                    bf16x8 bx = *(const bf16x8*)&sb[row * CPs + cb];
                    #pragma unroll
                    for (int fm = 0; fm < 2; ++fm)
                        acc[fm][fn] = __builtin_amdgcn_mfma_f32_32x32x16_bf16(
                            af[fm], bx, acc[fm][fn], 0, 0, 0);
                }
            }
        }
    };

    issue_row(f0 - 1); write_row(0);
    issue_row(f0);     write_row(1);
    issue_row(f0 + 1); write_row(2);
    __syncthreads();

    int sA = 0, sB = 1, sC = 2;

    #pragma unroll 1
    for (int i = 0; i < FPB; ++i) {
        const int f = f0 + i;
        if (i < FPB - 1) issue_row(f + 2);

        #pragma unroll
        for (int a = 0; a < 2; ++a)
            #pragma unroll
            for (int c2 = 0; c2 < 2; ++c2)
                #pragma unroll
                for (int e = 0; e < 16; ++e) acc[a][c2][e] = 0.f;

        mfma_kh(0, sA);
        mfma_kh(1, sB);
        mfma_kh(2, sC);

        #pragma unroll
        for (int fm = 0; fm < 2; ++fm) {
            #pragma unroll
            for (int fn = 0; fn < 2; ++fn) {
                int t = tb + tw * 64 + fn * 32 + lo32;
                #pragma unroll
                for (int reg = 0; reg < 16; ++reg) {
                    int o = oh * 64 + fm * 32 + (reg & 3) + 8 * (reg >> 2) + 4 * kg;
                    out[(((size_t)n * 128 + o) * 128 + f) * 256 + t] = acc[fm][fn][reg] + b[o];
                }
            }
        }

        __syncthreads();
        if (i < FPB - 1) write_row(sA);
        __syncthreads();
        int tmp = sA; sA = sB; sB = sC; sC = tmp;
    }
}

extern "C" void kernel_launch(void* const* d_in, const int* in_sizes, int n_in,
                              void* d_out, int out_size, void* d_ws, size_t ws_size,
                              hipStream_t stream) {
    const float* x = (const float*)d_in[0];
    const float* W = (const float*)d_in[1];
    const float* b = (const float*)d_in[2];
    float* out = (float*)d_out;

    if (ws_size >= WS_NEEDED) {
        unsigned short* xd = (unsigned short*)d_ws;
        unsigned short* Wr = xd + XD_ELEMS;
        hipLaunchKernelGGL(prep_w, dim3(288), dim3(256), 0, stream, W, Wr);
        hipLaunchKernelGGL(prep_x, dim3(4096), dim3(256), 0, stream, x, xd);
        hipLaunchKernelGGL(conv_dma, dim3(512), dim3(256), 0, stream, xd, Wr, b, out);
    } else {
        unsigned short* Wr = (unsigned short*)d_ws;
        hipLaunchKernelGGL(prep_w, dim3(288), dim3(256), 0, stream, W, Wr);
        hipLaunchKernelGGL(damp_conv_mfma, dim3(1024), dim3(256), 0, stream, x, Wr, b, out);
    }
}